// Round 2
// baseline (759.584 us; speedup 1.0000x reference)
//
#include <hip/hip_runtime.h>
#include <math.h>

#define NROWS   500000
#define NGRP    50000
#define NEG     0.2f

typedef unsigned int uint32;
typedef unsigned short ushort16;

__device__ __forceinline__ float leaky(float h) { return h >= 0.f ? h : NEG * h; }

// bf16 pack/unpack (round-to-nearest-even) for the ws-constrained fallback
__device__ __forceinline__ ushort16 f2bf(float v) {
    uint32 u = __float_as_uint(v);
    u += 0x7FFFu + ((u >> 16) & 1u);
    return (ushort16)(u >> 16);
}
__device__ __forceinline__ float ld_m(const float* p)    { return *p; }
__device__ __forceinline__ float ld_m(const ushort16* p) { return __uint_as_float(((uint32)*p) << 16); }
__device__ __forceinline__ void  st_m(float* p, float v)    { *p = v; }
__device__ __forceinline__ void  st_m(ushort16* p, float v) { *p = f2bf(v); }

// ---------------------------------------------------------------------------
// K0: Wsum = W1a + W1b + W1c  (row-major [k][j], 64x64)
__global__ void k0_wsum(const float* __restrict__ w1, float* __restrict__ wsum) {
    int i = blockIdx.x * 256 + threadIdx.x;
    if (i < 64 * 64) wsum[i] = w1[i] + w1[4096 + i] + w1[8192 + i];
}

// ---------------------------------------------------------------------------
// K1a: per-group min/max + seg fill. ONE wave per group (50k waves total).
// lane = feature dim; row loop unrolled x4 for memory ILP. VGPR-light.
template <typename MT>
__global__ __launch_bounds__(256)
void k1a_minmax(const float* __restrict__ x, const int* __restrict__ csr,
                MT* __restrict__ mnmx, int* __restrict__ seg) {
    const int lane = threadIdx.x & 63;
    const int g    = blockIdx.x * 4 + (threadIdx.x >> 6);
    if (g >= NGRP) return;

    const int p0 = csr[g], p1 = csr[g + 1];
    const int cnt = p1 - p0;

    // seg fill (consecutive addresses across lanes -> coalesced)
    for (int t = p0 + lane; t < p1; t += 64) seg[t] = g;

    if (cnt <= 0) return;  // empty group: mnmx left as poison, never used

    const float* p = x + (size_t)p0 * 64 + lane;
    float mn = INFINITY, mx = -INFINITY;
    int i = 0;
    for (; i + 4 <= cnt; i += 4) {
        float a = p[0], b = p[64], c = p[128], d = p[192];
        p += 256;
        mn = fminf(mn, fminf(fminf(a, b), fminf(c, d)));
        mx = fmaxf(mx, fmaxf(fmaxf(a, b), fmaxf(c, d)));
    }
    for (; i < cnt; ++i) {
        float a = p[0]; p += 64;
        mn = fminf(mn, a);
        mx = fmaxf(mx, a);
    }
    st_m(mnmx + (size_t)g * 128 + lane, mn);
    st_m(mnmx + (size_t)g * 128 + 64 + lane, mx);
}

// ---------------------------------------------------------------------------
// K1b: bias1[g][j] = -(mn_g @ W1b + mx_g @ W1c).  Batched GEMV: 64 groups per
// block, 2 waves split j (32 each). mnmx tile staged in LDS (stride 129).
// Note w1 rows 64..191 are [W1b; W1c] contiguous -> weight row = w1+(64+k)*64.
template <typename MT>
__global__ __launch_bounds__(128)
void k1b_bias(const MT* __restrict__ mnmx, const float* __restrict__ w1,
              float* __restrict__ bias1) {
    __shared__ float tile[64 * 129];
    const int tid  = threadIdx.x;
    const int w    = tid >> 6;
    const int lane = tid & 63;
    const int g0   = blockIdx.x * 64;
    const int availg = NGRP - g0;                     // groups available
    const int availf = availg * 128;                  // mnmx floats available

    // stage 64x128 mnmx -> LDS
    const MT* src = mnmx + (size_t)g0 * 128;
#pragma unroll
    for (int i = 0; i < 16; ++i) {
        int f = (i * 128 + tid) * 4;
        if (f < availf) {
            int gg = f >> 7, c = f & 127;
            tile[gg * 129 + c + 0] = ld_m(src + f + 0);
            tile[gg * 129 + c + 1] = ld_m(src + f + 1);
            tile[gg * 129 + c + 2] = ld_m(src + f + 2);
            tile[gg * 129 + c + 3] = ld_m(src + f + 3);
        }
    }
    __syncthreads();

    const int jb = w * 32;
    float acc[32];
#pragma unroll
    for (int j = 0; j < 32; ++j) acc[j] = 0.f;

#pragma unroll 2
    for (int k = 0; k < 128; ++k) {
        float m = tile[lane * 129 + k];
        const float* __restrict__ wr = w1 + (64 + k) * 64 + jb;  // uniform -> s_load
#pragma unroll
        for (int j = 0; j < 32; ++j) acc[j] = fmaf(m, wr[j], acc[j]);
    }
    __syncthreads();

    // park -acc in LDS (stride 65 region reuse), then coalesced float4 store
#pragma unroll
    for (int j = 0; j < 32; ++j) tile[lane * 65 + jb + j] = -acc[j];
    __syncthreads();

    float* dst = bias1 + (size_t)g0 * 64;
    const int availo = availg * 64;
#pragma unroll
    for (int i = 0; i < 8; ++i) {
        int f = (i * 128 + tid) * 4;
        if (f < availo) {
            int gg = f >> 6, c = f & 63;
            float4 v = make_float4(tile[gg * 65 + c], tile[gg * 65 + c + 1],
                                   tile[gg * 65 + c + 2], tile[gg * 65 + c + 3]);
            *(float4*)(dst + f) = v;
        }
    }
}

// ---------------------------------------------------------------------------
// K2: y = leaky(leaky(x@Wsum + bias1[seg]) @ w2). 64-row tile per block,
// 2 waves split j (32 acc each). lane = row. x tile in LDS stride 65
// (bank = (lane+k)%32, 2-way = free). Epilogue transposed through LDS ->
// coalesced float4 stores.
__global__ __launch_bounds__(128)
void k2_mlp(const float* __restrict__ x, const int* __restrict__ seg,
            const float* __restrict__ bias1, const float* __restrict__ wsum,
            const float* __restrict__ w2, float* __restrict__ out) {
    __shared__ float tile[64 * 65];
    const int tid  = threadIdx.x;
    const int w    = tid >> 6;
    const int lane = tid & 63;
    const int row0 = blockIdx.x * 64;
    const int avail = (NROWS - row0) * 64;  // floats in this tile

    // stage x tile (coalesced float4 global reads)
    const float4* x4 = (const float4*)(x + (size_t)row0 * 64);
#pragma unroll
    for (int i = 0; i < 8; ++i) {
        int f = (i * 128 + tid) * 4;
        if (f < avail) {
            float4 v = x4[f >> 2];
            int r = f >> 6, c = f & 63;
            tile[r * 65 + c + 0] = v.x;
            tile[r * 65 + c + 1] = v.y;
            tile[r * 65 + c + 2] = v.z;
            tile[r * 65 + c + 3] = v.w;
        }
    }
    __syncthreads();

    const int row = row0 + lane;
    const bool valid = row < NROWS;
    const int sg = valid ? seg[row] : 0;
    const int jb = w * 32;

    // acc init from bias1[seg] (float4 gather; bias rows L2-hot, ~10x reuse)
    float acc[32];
    const float4* b4 = (const float4*)(bias1 + (size_t)sg * 64 + jb);
#pragma unroll
    for (int i = 0; i < 8; ++i) {
        float4 v = valid ? b4[i] : make_float4(0.f, 0.f, 0.f, 0.f);
        acc[4 * i + 0] = v.x; acc[4 * i + 1] = v.y;
        acc[4 * i + 2] = v.z; acc[4 * i + 3] = v.w;
    }

    // GEMV1: acc[j] += x[row][k] * Wsum[k][jb+j]
#pragma unroll 2
    for (int k = 0; k < 64; ++k) {
        float xk = tile[lane * 65 + k];
        const float* __restrict__ wr = wsum + (k << 6) + jb;  // uniform -> s_load
#pragma unroll
        for (int j = 0; j < 32; ++j) acc[j] = fmaf(xk, wr[j], acc[j]);
    }

    __syncthreads();  // both waves done reading x tile
#pragma unroll
    for (int j = 0; j < 32; ++j) tile[lane * 65 + jb + j] = leaky(acc[j]);
    __syncthreads();

    // GEMV2
    float acc2[32];
#pragma unroll
    for (int j = 0; j < 32; ++j) acc2[j] = 0.f;
#pragma unroll 2
    for (int k = 0; k < 64; ++k) {
        float yk = tile[lane * 65 + k];
        const float* __restrict__ wr = w2 + (k << 6) + jb;    // uniform -> s_load
#pragma unroll
        for (int j = 0; j < 32; ++j) acc2[j] = fmaf(yk, wr[j], acc2[j]);
    }

    __syncthreads();
#pragma unroll
    for (int j = 0; j < 32; ++j) tile[lane * 65 + jb + j] = leaky(acc2[j]);
    __syncthreads();

    // coalesced float4 epilogue
    float* o = out + (size_t)row0 * 64;
#pragma unroll
    for (int i = 0; i < 8; ++i) {
        int f = (i * 128 + tid) * 4;
        if (f < avail) {
            int r = f >> 6, c = f & 63;
            float4 v = make_float4(tile[r * 65 + c], tile[r * 65 + c + 1],
                                   tile[r * 65 + c + 2], tile[r * 65 + c + 3]);
            *(float4*)(o + f) = v;
        }
    }
}

// ---------------------------------------------------------------------------
extern "C" void kernel_launch(void* const* d_in, const int* in_sizes, int n_in,
                              void* d_out, int out_size, void* d_ws, size_t ws_size,
                              hipStream_t stream) {
    const float* x   = (const float*)d_in[0];
    const int*   csr = (const int*)d_in[1];
    const float* w1  = (const float*)d_in[2];
    const float* w2  = (const float*)d_in[3];
    float* out = (float*)d_out;

    // ws layout: wsum(4096 f) | bias1(NGRP*64 f) | seg(NROWS i32) | mnmx
    float* wsum  = (float*)d_ws;
    float* bias1 = wsum + 4096;
    int*   seg   = (int*)(bias1 + (size_t)NGRP * 64);
    void*  mnmx  = (void*)(seg + NROWS);
    const size_t base_bytes = (size_t)((char*)mnmx - (char*)d_ws);
    const size_t need_f32   = base_bytes + (size_t)NGRP * 128 * sizeof(float);
    const bool use_f32 = ws_size >= need_f32;

    const int grid_k1a = (NGRP + 3) / 4;        // 1 wave per group
    const int grid_k1b = (NGRP + 63) / 64;
    const int grid_k2  = (NROWS + 63) / 64;

    k0_wsum<<<16, 256, 0, stream>>>(w1, wsum);
    if (use_f32) {
        k1a_minmax<float><<<grid_k1a, 256, 0, stream>>>(x, csr, (float*)mnmx, seg);
        k1b_bias<float><<<grid_k1b, 128, 0, stream>>>((const float*)mnmx, w1, bias1);
    } else {
        k1a_minmax<ushort16><<<grid_k1a, 256, 0, stream>>>(x, csr, (ushort16*)mnmx, seg);
        k1b_bias<ushort16><<<grid_k1b, 128, 0, stream>>>((const ushort16*)mnmx, w1, bias1);
    }
    k2_mlp<<<grid_k2, 128, 0, stream>>>(x, seg, bias1, wsum, w2, out);
}

// Round 3
// 374.092 us; speedup vs baseline: 2.0305x; 2.0305x over previous
//
#include <hip/hip_runtime.h>
#include <math.h>

#define NROWS   500000
#define NGRP    50000
#define NEG     0.2f

typedef unsigned int uint32;
typedef unsigned short ushort16;

__device__ __forceinline__ float leaky(float h) { return h >= 0.f ? h : NEG * h; }

// bf16 pack/unpack (round-to-nearest-even) for the ws-constrained fallback
__device__ __forceinline__ ushort16 f2bf(float v) {
    uint32 u = __float_as_uint(v);
    u += 0x7FFFu + ((u >> 16) & 1u);
    return (ushort16)(u >> 16);
}
__device__ __forceinline__ float ld_m(const float* p)    { return *p; }
__device__ __forceinline__ float ld_m(const ushort16* p) { return __uint_as_float(((uint32)*p) << 16); }
__device__ __forceinline__ void  st_m(float* p, float v)    { *p = v; }
__device__ __forceinline__ void  st_m(ushort16* p, float v) { *p = f2bf(v); }

// ---------------------------------------------------------------------------
// K0: Wsum = W1a + W1b + W1c  (row-major [k][j], 64x64)
__global__ void k0_wsum(const float* __restrict__ w1, float* __restrict__ wsum) {
    int i = blockIdx.x * 256 + threadIdx.x;
    if (i < 64 * 64) wsum[i] = w1[i] + w1[4096 + i] + w1[8192 + i];
}

// ---------------------------------------------------------------------------
// K1a: per-group min/max + seg fill. ONE wave per group (50k waves total).
// lane = feature dim; row loop unrolled x4 for memory ILP. VGPR-light.
template <typename MT>
__global__ __launch_bounds__(256)
void k1a_minmax(const float* __restrict__ x, const int* __restrict__ csr,
                MT* __restrict__ mnmx, int* __restrict__ seg) {
    const int lane = threadIdx.x & 63;
    const int g    = blockIdx.x * 4 + (threadIdx.x >> 6);
    if (g >= NGRP) return;

    const int p0 = csr[g], p1 = csr[g + 1];
    const int cnt = p1 - p0;

    // seg fill (consecutive addresses across lanes -> coalesced)
    for (int t = p0 + lane; t < p1; t += 64) seg[t] = g;

    if (cnt <= 0) return;  // empty group: mnmx left as poison, never used

    const float* p = x + (size_t)p0 * 64 + lane;
    float mn = INFINITY, mx = -INFINITY;
    int i = 0;
    for (; i + 4 <= cnt; i += 4) {
        float a = p[0], b = p[64], c = p[128], d = p[192];
        p += 256;
        mn = fminf(mn, fminf(fminf(a, b), fminf(c, d)));
        mx = fmaxf(mx, fmaxf(fmaxf(a, b), fmaxf(c, d)));
    }
    for (; i < cnt; ++i) {
        float a = p[0]; p += 64;
        mn = fminf(mn, a);
        mx = fmaxf(mx, a);
    }
    st_m(mnmx + (size_t)g * 128 + lane, mn);
    st_m(mnmx + (size_t)g * 128 + 64 + lane, mx);
}

// ---------------------------------------------------------------------------
// K1b: bias1[g][j] = -(mn_g @ W1b + mx_g @ W1c).  Batched GEMV: 64 groups per
// block, 2 waves split j (32 each). jb forced into SGPR via readfirstlane so
// the weight-row reads scalar-promote to s_load (scalar pipe, co-issues with
// VALU). w1 rows 64..191 are [W1b; W1c] contiguous.
template <typename MT>
__global__ __launch_bounds__(128)
void k1b_bias(const MT* __restrict__ mnmx, const float* __restrict__ w1,
              float* __restrict__ bias1) {
    __shared__ float tile[64 * 129];
    const int tid  = threadIdx.x;
    const int lane = tid & 63;
    // WAVE-UNIFORM j-offset in an SGPR: this is what lets the backend emit
    // s_load for the weight rows instead of per-lane global_load_dword.
    const int jb = __builtin_amdgcn_readfirstlane((tid >> 6) * 32);
    const int g0   = blockIdx.x * 64;
    const int availg = NGRP - g0;                     // groups available
    const int availf = availg * 128;                  // mnmx floats available

    // stage 64x128 mnmx -> LDS
    const MT* src = mnmx + (size_t)g0 * 128;
#pragma unroll
    for (int i = 0; i < 16; ++i) {
        int f = (i * 128 + tid) * 4;
        if (f < availf) {
            int gg = f >> 7, c = f & 127;
            tile[gg * 129 + c + 0] = ld_m(src + f + 0);
            tile[gg * 129 + c + 1] = ld_m(src + f + 1);
            tile[gg * 129 + c + 2] = ld_m(src + f + 2);
            tile[gg * 129 + c + 3] = ld_m(src + f + 3);
        }
    }
    __syncthreads();

    float acc[32];
#pragma unroll
    for (int j = 0; j < 32; ++j) acc[j] = 0.f;

#pragma unroll 2
    for (int k = 0; k < 128; ++k) {
        float m = tile[lane * 129 + k];
        const float* __restrict__ wr = w1 + (64 + k) * 64 + jb;  // uniform -> s_load
#pragma unroll
        for (int j = 0; j < 32; ++j) acc[j] = fmaf(m, wr[j], acc[j]);
    }
    __syncthreads();

    // park -acc in LDS (stride 65 region reuse), then coalesced float4 store
#pragma unroll
    for (int j = 0; j < 32; ++j) tile[lane * 65 + jb + j] = -acc[j];
    __syncthreads();

    float* dst = bias1 + (size_t)g0 * 64;
    const int availo = availg * 64;
#pragma unroll
    for (int i = 0; i < 8; ++i) {
        int f = (i * 128 + tid) * 4;
        if (f < availo) {
            int gg = f >> 6, c = f & 63;
            float4 v = make_float4(tile[gg * 65 + c], tile[gg * 65 + c + 1],
                                   tile[gg * 65 + c + 2], tile[gg * 65 + c + 3]);
            *(float4*)(dst + f) = v;
        }
    }
}

// ---------------------------------------------------------------------------
// K2: y = leaky(leaky(x@Wsum + bias1[seg]) @ w2). 64-row tile per block,
// 2 waves split j (32 acc each). lane = row. jb in SGPR (readfirstlane) so
// weight reads go down the scalar pipe (s_load) and the inner loop is pure
// v_fmac. x tile in LDS stride 65 (2-way bank alias = free). Epilogue
// transposed through LDS -> coalesced float4 stores.
__global__ __launch_bounds__(128)
void k2_mlp(const float* __restrict__ x, const int* __restrict__ seg,
            const float* __restrict__ bias1, const float* __restrict__ wsum,
            const float* __restrict__ w2, float* __restrict__ out) {
    __shared__ float tile[64 * 65];
    const int tid  = threadIdx.x;
    const int lane = tid & 63;
    const int jb   = __builtin_amdgcn_readfirstlane((tid >> 6) * 32);  // SGPR
    const int row0 = blockIdx.x * 64;
    const int avail = (NROWS - row0) * 64;  // floats in this tile

    // stage x tile (coalesced float4 global reads)
    const float4* x4 = (const float4*)(x + (size_t)row0 * 64);
#pragma unroll
    for (int i = 0; i < 8; ++i) {
        int f = (i * 128 + tid) * 4;
        if (f < avail) {
            float4 v = x4[f >> 2];
            int r = f >> 6, c = f & 63;
            tile[r * 65 + c + 0] = v.x;
            tile[r * 65 + c + 1] = v.y;
            tile[r * 65 + c + 2] = v.z;
            tile[r * 65 + c + 3] = v.w;
        }
    }
    __syncthreads();

    const int row = row0 + lane;
    const bool valid = row < NROWS;
    const int sg = valid ? seg[row] : 0;

    // acc init from bias1[seg] (float4 gather; bias rows L2-hot, ~10x reuse)
    float acc[32];
    const float4* b4 = (const float4*)(bias1 + (size_t)sg * 64 + jb);
#pragma unroll
    for (int i = 0; i < 8; ++i) {
        float4 v = valid ? b4[i] : make_float4(0.f, 0.f, 0.f, 0.f);
        acc[4 * i + 0] = v.x; acc[4 * i + 1] = v.y;
        acc[4 * i + 2] = v.z; acc[4 * i + 3] = v.w;
    }

    // GEMV1: acc[j] += x[row][k] * Wsum[k][jb+j]
#pragma unroll 2
    for (int k = 0; k < 64; ++k) {
        float xk = tile[lane * 65 + k];
        const float* __restrict__ wr = wsum + (k << 6) + jb;  // uniform -> s_load
#pragma unroll
        for (int j = 0; j < 32; ++j) acc[j] = fmaf(xk, wr[j], acc[j]);
    }

    __syncthreads();  // both waves done reading x tile
#pragma unroll
    for (int j = 0; j < 32; ++j) tile[lane * 65 + jb + j] = leaky(acc[j]);
    __syncthreads();

    // GEMV2
    float acc2[32];
#pragma unroll
    for (int j = 0; j < 32; ++j) acc2[j] = 0.f;
#pragma unroll 2
    for (int k = 0; k < 64; ++k) {
        float yk = tile[lane * 65 + k];
        const float* __restrict__ wr = w2 + (k << 6) + jb;    // uniform -> s_load
#pragma unroll
        for (int j = 0; j < 32; ++j) acc2[j] = fmaf(yk, wr[j], acc2[j]);
    }

    __syncthreads();
#pragma unroll
    for (int j = 0; j < 32; ++j) tile[lane * 65 + jb + j] = leaky(acc2[j]);
    __syncthreads();

    // coalesced float4 epilogue
    float* o = out + (size_t)row0 * 64;
#pragma unroll
    for (int i = 0; i < 8; ++i) {
        int f = (i * 128 + tid) * 4;
        if (f < avail) {
            int r = f >> 6, c = f & 63;
            float4 v = make_float4(tile[r * 65 + c], tile[r * 65 + c + 1],
                                   tile[r * 65 + c + 2], tile[r * 65 + c + 3]);
            *(float4*)(o + f) = v;
        }
    }
}

// ---------------------------------------------------------------------------
extern "C" void kernel_launch(void* const* d_in, const int* in_sizes, int n_in,
                              void* d_out, int out_size, void* d_ws, size_t ws_size,
                              hipStream_t stream) {
    const float* x   = (const float*)d_in[0];
    const int*   csr = (const int*)d_in[1];
    const float* w1  = (const float*)d_in[2];
    const float* w2  = (const float*)d_in[3];
    float* out = (float*)d_out;

    // ws layout: wsum(4096 f) | bias1(NGRP*64 f) | seg(NROWS i32) | mnmx
    float* wsum  = (float*)d_ws;
    float* bias1 = wsum + 4096;
    int*   seg   = (int*)(bias1 + (size_t)NGRP * 64);
    void*  mnmx  = (void*)(seg + NROWS);
    const size_t base_bytes = (size_t)((char*)mnmx - (char*)d_ws);
    const size_t need_f32   = base_bytes + (size_t)NGRP * 128 * sizeof(float);
    const bool use_f32 = ws_size >= need_f32;

    const int grid_k1a = (NGRP + 3) / 4;        // 1 wave per group
    const int grid_k1b = (NGRP + 63) / 64;
    const int grid_k2  = (NROWS + 63) / 64;

    k0_wsum<<<16, 256, 0, stream>>>(w1, wsum);
    if (use_f32) {
        k1a_minmax<float><<<grid_k1a, 256, 0, stream>>>(x, csr, (float*)mnmx, seg);
        k1b_bias<float><<<grid_k1b, 128, 0, stream>>>((const float*)mnmx, w1, bias1);
    } else {
        k1a_minmax<ushort16><<<grid_k1a, 256, 0, stream>>>(x, csr, (ushort16*)mnmx, seg);
        k1b_bias<ushort16><<<grid_k1b, 128, 0, stream>>>((const ushort16*)mnmx, w1, bias1);
    }
    k2_mlp<<<grid_k2, 128, 0, stream>>>(x, seg, bias1, wsum, w2, out);
}